// Round 2
// baseline (1047.499 us; speedup 1.0000x reference)
//
#include <hip/hip_runtime.h>

#define B_ 8
#define L_ 2048
#define D_ 64
#define K_ 40
#define NU_ 32
#define T_ 2047   // L-1
#define NSPLIT 8

// ---- workspace layout (in floats) ----
#define XT_OFF   0
#define XT_SZ    (B_*L_*NU_)                 // 524288
#define HH_OFF   (XT_OFF + XT_SZ)
#define HH_SZ    (B_*K_*T_*NU_)              // 20,961,280
#define HTHP_OFF (HH_OFF + HH_SZ)
#define HTHP_SZ  (NSPLIT*B_*K_*NU_*NU_)      // 2,621,440
#define HTXP_OFF (HTHP_OFF + HTHP_SZ)
#define HTXP_SZ  (NSPLIT*B_*K_*NU_*D_)      // 5,242,880
#define SH_OFF   (HTXP_OFF + HTXP_SZ)
#define SH_SZ    (B_*K_*NU_)
#define SX_OFF   (SH_OFF + SH_SZ)
#define SX_SZ    (B_*K_)

#if __has_builtin(__builtin_amdgcn_exp2f)
#define EXP2F(x) __builtin_amdgcn_exp2f(x)
#else
#define EXP2F(x) __expf((x)*0.6931471805599453f)
#endif
#if __has_builtin(__builtin_amdgcn_rcpf)
#define RCPF(x) __builtin_amdgcn_rcpf(x)
#else
#define RCPF(x) (1.0f/(x))
#endif

// ================= K1: xt = x @ W_in  (B*L rows, 64 -> 32) =================
__global__ __launch_bounds__(256) void k1_xt(const float* __restrict__ x,
                                             const float* __restrict__ Win,
                                             float* __restrict__ xt)
{
    __shared__ float Ws[D_*NU_];
    for (int i = threadIdx.x; i < D_*NU_; i += 256) Ws[i] = Win[i];
    __syncthreads();
    int gid = blockIdx.x*256 + threadIdx.x;       // < 524288
    int m   = gid & 31;
    int row = gid >> 5;
    const float4* xr = (const float4*)(x + (size_t)row * 64);
    float s = 0.f;
#pragma unroll
    for (int q = 0; q < 16; ++q) {
        float4 v = xr[q];
        s = fmaf(v.x, Ws[(q*4+0)*32+m], s);
        s = fmaf(v.y, Ws[(q*4+1)*32+m], s);
        s = fmaf(v.z, Ws[(q*4+2)*32+m], s);
        s = fmaf(v.w, Ws[(q*4+3)*32+m], s);
    }
    xt[gid] = s;
}

// ================= K2: delay-decomposed recurrence ==========================
// one 64-lane wave per (b, r, chain c). h_r(t) = tanh(xt(t) + h_r(t-(r+1)) @ Wr)
// lane (m, half): accumulates n in [half*16, half*16+16) of the dot for output m.
__global__ __launch_bounds__(64) void k2_rec(const float* __restrict__ ws_xt,
                                             const float* __restrict__ Wres,
                                             const float* __restrict__ radii,
                                             float* __restrict__ hh)
{
    const int l    = threadIdx.x;
    const int m    = l & 31;
    const int half = l >> 5;
    int e = blockIdx.x % 820;
    int b = blockIdx.x / 820;
    int r = 0, base = 0;
    while (e >= base + r + 1) { base += r + 1; ++r; }
    const int cc     = e - base;
    const int stride = r + 1;
    const float rad  = radii[r];
    const int j0 = half << 4;            // this lane sums n in [j0, j0+16)
    float w[16];
#pragma unroll
    for (int j = 0; j < 16; ++j)         // need column m of Wr: Wr[r][n][m]
        w[j] = Wres[r*1024 + (j0 + j)*32 + m] * rad;

    const float* xt = ws_xt + (size_t)b * L_ * NU_;
    float* hrow = hh + ((size_t)(b*K_ + r)) * T_ * NU_;

    int t = cc;
    const int nsteps = (T_ - 1 - cc) / stride + 1;
    // 3-deep xt prefetch (register rotation, all static)
    int ta = t;                       float xv0 = xt[ta*32 + m];
    int tb = t + stride;   if (tb > L_-1) tb = L_-1;   float xv1 = xt[tb*32 + m];
    int tc = t + 2*stride; if (tc > L_-1) tc = L_-1;   float xv2 = xt[tc*32 + m];

    int hbits = 0;  // h = 0 initial state
    for (int sstep = 0; sstep < nsteps; ++sstep) {
        int t3 = t + 3*stride; if (t3 > L_-1) t3 = L_-1;
        float xv3 = xt[t3*32 + m];

        float a0 = half ? 0.0f : xv0;    // xt added once (half 0 only)
        float a1 = 0.f, a2 = 0.f, a3 = 0.f;
#define GATH(J, ACC) { int g_ = __builtin_amdgcn_ds_bpermute((j0 + (J)) << 2, hbits); \
                       ACC = fmaf(w[J], __int_as_float(g_), ACC); }
        GATH(0,a0)  GATH(1,a1)  GATH(2,a2)  GATH(3,a3)
        GATH(4,a0)  GATH(5,a1)  GATH(6,a2)  GATH(7,a3)
        GATH(8,a0)  GATH(9,a1)  GATH(10,a2) GATH(11,a3)
        GATH(12,a0) GATH(13,a1) GATH(14,a2) GATH(15,a3)
#undef GATH
        float s = (a0 + a1) + (a2 + a3);
        s += __shfl_xor(s, 32);
        // tanh(s) = 1 - 2/(exp2(2*log2e*s)+1); self-saturating in fp32:
        // s->+inf: exp2->inf, rcp->0, h->1.  s->-inf: exp2->0, h->-1.  No clamp needed.
        float ex   = EXP2F(s * 2.8853900817779268f);
        float hnew = fmaf(-2.f, RCPF(ex + 1.f), 1.f);
        if (l < 32) hrow[t*32 + l] = hnew;
        hbits = __float_as_int(hnew);
        xv0 = xv1; xv1 = xv2; xv2 = xv3;
        t += stride;
    }
}

// ================= K3: HtH / HtX partials = H^T [H|X] ======================
// grid (split s, k, b); 64 threads; 48 compute an 8x8 tile of the 32x96 output
__global__ __launch_bounds__(64) void k3_gemm(const float* __restrict__ hh,
                                              const float* __restrict__ x,
                                              float* __restrict__ htHp,
                                              float* __restrict__ htXp,
                                              float* __restrict__ sH,
                                              float* __restrict__ sX)
{
    const int s  = blockIdx.x;
    const int k  = blockIdx.y;
    const int b  = blockIdx.z;
    const int l  = threadIdx.x;
    const int bk = b*K_ + k;
    const int Tk = T_ - k;                  // valid rows
    __shared__ __align__(16) float P[32][96];
    const int tidn = l / 12;                // 0..3  (for l<48)
    const int tidc = l % 12;                // 0..11

    float acc[8][8];
#pragma unroll
    for (int i = 0; i < 8; ++i)
#pragma unroll
        for (int j = 0; j < 8; ++j) acc[i][j] = 0.f;
    float bsum[8];
#pragma unroll
    for (int j = 0; j < 8; ++j) bsum[j] = 0.f;

    const float* hrow = hh + (size_t)bk * T_ * NU_;
    const float* xrow = x + (size_t)b * L_ * D_ + (size_t)(k+1) * D_;  // Xm row tt = x[b, tt+k+1]

    for (int ch = s*8; ch < s*8 + 8; ++ch) {
        const int t0 = ch*32;
        // ---- stage 32 rows x [H(32) | X(64)] ----
#pragma unroll
        for (int rd = 0; rd < 12; ++rd) {
            int slot = rd*64 + l;
            int row  = slot / 24;
            int q    = slot % 24;
            int tt   = t0 + row;
            float4 v = make_float4(0.f, 0.f, 0.f, 0.f);
            if (tt < Tk) {
                if (q < 8) v = *(const float4*)(hrow + (size_t)tt*32 + q*4);
                else       v = *(const float4*)(xrow + (size_t)tt*64 + (q-8)*4);
            }
            *(float4*)&P[row][q*4] = v;
        }
        __syncthreads();
        if (l < 48) {
#pragma unroll 4
            for (int tt = 0; tt < 32; ++tt) {
                const float* pr = &P[tt][0];
                float4 A0 = *(const float4*)(pr + tidn*8);
                float4 A1 = *(const float4*)(pr + tidn*8 + 4);
                float4 B0 = *(const float4*)(pr + tidc*8);
                float4 B1 = *(const float4*)(pr + tidc*8 + 4);
                float av[8] = {A0.x,A0.y,A0.z,A0.w,A1.x,A1.y,A1.z,A1.w};
                float bv[8] = {B0.x,B0.y,B0.z,B0.w,B1.x,B1.y,B1.z,B1.w};
#pragma unroll
                for (int i = 0; i < 8; ++i)
#pragma unroll
                    for (int j = 0; j < 8; ++j)
                        acc[i][j] = fmaf(av[i], bv[j], acc[i][j]);
#pragma unroll
                for (int j = 0; j < 8; ++j) bsum[j] += bv[j];  // column sums (free-ish)
            }
        }
        __syncthreads();
    }
    if (l < 48) {
        const int base_h = (s*(B_*K_) + bk)*NU_*NU_;
        const int base_x = (s*(B_*K_) + bk)*NU_*D_;
#pragma unroll
        for (int i = 0; i < 8; ++i) {
            int n = tidn*8 + i;
#pragma unroll
            for (int j = 0; j < 8; ++j) {
                int c = tidc*8 + j;
                if (c < 32) htHp[base_h + n*32 + c]      = acc[i][j];
                else        htXp[base_x + n*64 + (c-32)] = acc[i][j];
            }
        }
        if (tidn == 0) {                       // bsum identical across tidn
            if (tidc < 4) {
#pragma unroll
                for (int j = 0; j < 8; ++j)
                    atomicAdd(&sH[bk*32 + tidc*8 + j], bsum[j]);
            } else {
                float t = 0.f;
#pragma unroll
                for (int j = 0; j < 8; ++j) t += bsum[j];
                atomicAdd(&sX[bk], t);
            }
        }
    }
}

// ================= K4: Cholesky solve + features + f_norms =================
__global__ __launch_bounds__(64) void k4_solve(const float* __restrict__ htHp,
                                               const float* __restrict__ htXp,
                                               const float* __restrict__ sH,
                                               const float* __restrict__ sX,
                                               float* __restrict__ dout)
{
    const int k  = blockIdx.x;
    const int b  = blockIdx.y;
    const int bk = b*K_ + k;
    const int l  = threadIdx.x;
    __shared__ float As[32][33];
    // A = sum_s HtHp + REG*I   (REG = 1.0)
#pragma unroll
    for (int i = 0; i < 16; ++i) {
        int idx = i*64 + l;
        int row = idx >> 5, col = idx & 31;
        float v = (row == col) ? 1.0f : 0.0f;
        for (int s2 = 0; s2 < NSPLIT; ++s2)
            v += htHp[(size_t)(s2*(B_*K_) + bk)*1024 + idx];
        As[row][col] = v;
    }
    __syncthreads();
    // Cholesky (lower), lane i owns row i; single wave => lockstep, reads precede writes
    for (int j = 0; j < 32; ++j) {
        float d   = sqrtf(As[j][j]);
        float inv = 1.0f / d;
        if (l == j) As[j][j] = d;
        if (l < 32 && l > j) As[l][j] *= inv;
        __syncthreads();
        if (l < 32 && l > j) {
            float lij = As[l][j];
            for (int c = j+1; c <= l; ++c)
                As[l][c] -= lij * As[c][j];
        }
        __syncthreads();
    }
    // solve for RHS column d = l (64 columns)
    float y[32];
#pragma unroll
    for (int i = 0; i < 32; ++i) {
        float v = 0.f;
        for (int s2 = 0; s2 < NSPLIT; ++s2)
            v += htXp[(size_t)(s2*(B_*K_) + bk)*2048 + i*64 + l];
        y[i] = v;
    }
#pragma unroll
    for (int i = 0; i < 32; ++i) {           // forward: L y' = y
        float v = y[i];
#pragma unroll
        for (int j = 0; j < i; ++j) v = fmaf(-As[i][j], y[j], v);
        y[i] = v / As[i][i];
    }
#pragma unroll
    for (int i = 31; i >= 0; --i) {          // backward: L^T w = y'
        float v = y[i];
#pragma unroll
        for (int j = i+1; j < 32; ++j) v = fmaf(-As[j][i], y[j], v);
        y[i] = v / As[i][i];
    }
    // features
    float* fout = dout + (size_t)bk * NU_ * D_;
#pragma unroll
    for (int n = 0; n < 32; ++n) fout[n*64 + l] = y[n];
    // f_norms[k] += sum_d sum_n sH[n]*W[n,d] - sX   (atomically over b)
    const float* sh = sH + bk*32;
    float part = 0.f;
#pragma unroll
    for (int n = 0; n < 32; ++n) part = fmaf(sh[n], y[n], part);
#pragma unroll
    for (int off = 32; off > 0; off >>= 1) part += __shfl_xor(part, off);
    if (l == 0) atomicAdd(dout + (size_t)(B_*K_*NU_*D_) + k, part - sX[bk]);
}

// ============================================================================
extern "C" void kernel_launch(void* const* d_in, const int* in_sizes, int n_in,
                              void* d_out, int out_size, void* d_ws, size_t ws_size,
                              hipStream_t stream)
{
    const float* x     = (const float*)d_in[0];
    const float* radii = (const float*)d_in[1];
    const float* Win   = (const float*)d_in[2];
    const float* Wres  = (const float*)d_in[3];
    float* ws   = (float*)d_ws;
    float* xt   = ws + XT_OFF;
    float* hh   = ws + HH_OFF;
    float* htHp = ws + HTHP_OFF;
    float* htXp = ws + HTXP_OFF;
    float* sH   = ws + SH_OFF;
    float* sX   = ws + SX_OFF;
    float* out  = (float*)d_out;

    hipMemsetAsync(sH, 0, (size_t)(SH_SZ + SX_SZ)*sizeof(float), stream);
    hipMemsetAsync(out + (size_t)B_*K_*NU_*D_, 0, K_*sizeof(float), stream);

    k1_xt <<<(B_*L_*NU_)/256, 256, 0, stream>>>(x, Win, xt);
    k2_rec<<<B_*820, 64, 0, stream>>>(xt, Wres, radii, hh);
    k3_gemm<<<dim3(NSPLIT, K_, B_), 64, 0, stream>>>(hh, x, htHp, htXp, sH, sX);
    k4_solve<<<dim3(K_, B_), 64, 0, stream>>>(htHp, htXp, sH, sX, out);
}